// Round 9
// baseline (1035.902 us; speedup 1.0000x reference)
//
#include <hip/hip_runtime.h>

// VQ nearest-neighbor: argmin_k ||c_k||^2 - 2 x_n . c_k
// N=32768 rows, K=8192 codes, D=512, fp32 in, int32 indices out.
//
// Round 9: occupancy fix. r8 was register-limited to 1 block/CU (acc[4][2]
// = 128 f32 in the unified VGPR file -> ~250 regs/wave -> 2 waves/SIMD);
// every barrier idled the whole CU. New geometry: 256 codes x 128 xrows,
// BK=16, per-wave 64x64 (acc[2][2] = 64 regs), LDS 48KB, launch_bounds
// (512,4) -> 2 blocks/CU resident, cross-block MFMA/stall overlap.
// KSPLIT back to 8 (2MB codebook slice L2-resident per XCD; r8's KSPLIT=4
// slice was 8MB > 4MB L2 -> 805->1035 regression). 3 gloads/wave/step
// (waves 0-3 stage Xh, 4-7 Xl), counted vmcnt(3). Top-3 + lean tail kept.

#define D_DIM 512
#define EPS_GAP 1.5e-6f
#define KSPLIT 8

typedef __attribute__((ext_vector_type(8))) short short8;
typedef __attribute__((ext_vector_type(16))) float f32x16;
typedef __attribute__((ext_vector_type(4))) unsigned short us4;

__device__ __forceinline__ unsigned short f2bf(float x) {
    unsigned u = __float_as_uint(x);
    u += 0x7fffu + ((u >> 16) & 1u);          // RNE
    return (unsigned short)(u >> 16);
}
__device__ __forceinline__ float bf2f(unsigned short h) {
    return __uint_as_float(((unsigned)h) << 16);
}

__device__ __forceinline__ void gload_lds16(const void* g, void* l) {
    __builtin_amdgcn_global_load_lds(
        (const __attribute__((address_space(1))) unsigned int*)g,
        (__attribute__((address_space(3))) unsigned int*)l, 16, 0, 0);
}

// insert (d,i) into a top-3 state (d3 carries no index; a merged d3 can
// never reach top-2 of a union: it is >= two elements of its own list).
__device__ __forceinline__ void ins3(float d, int i, float& d1, int& i1,
                                     float& d2, int& i2, float& d3) {
    if (d < d1 || (d == d1 && i < i1)) { d3 = d2; d2 = d1; i2 = i1; d1 = d; i1 = i; }
    else if (d < d2 || (d == d2 && i < i2)) { d3 = d2; d2 = d; i2 = i; }
    else if (d < d3) d3 = d;
}

// ---- pass 0: fused split of CB (wave/row + ||c||^2) and X (grid-stride) ----
__global__ __launch_bounds__(256) void prep_kernel(
        const float* __restrict__ X, const float* __restrict__ CB,
        unsigned short* __restrict__ Xh, unsigned short* __restrict__ Xl,
        unsigned short* __restrict__ Ch, unsigned short* __restrict__ Cl,
        float* __restrict__ cbs, int n4, int K, int cbBlocks, int xBlocks) {
    const int bid = blockIdx.x;
    const int tid = threadIdx.x;
    if (bid < cbBlocks) {
        int w = bid * 4 + (tid >> 6);
        int lane = tid & 63;
        if (w >= K) return;
        size_t base = (size_t)w * D_DIM + lane * 8;
        const float4* r4 = (const float4*)(CB + base);
        float4 u = r4[0], v = r4[1];
        float s = u.x*u.x + u.y*u.y + u.z*u.z + u.w*u.w
                + v.x*v.x + v.y*v.y + v.z*v.z + v.w*v.w;
        us4 h0, l0, h1, l1;
        h0.x = f2bf(u.x); l0.x = f2bf(u.x - bf2f(h0.x));
        h0.y = f2bf(u.y); l0.y = f2bf(u.y - bf2f(h0.y));
        h0.z = f2bf(u.z); l0.z = f2bf(u.z - bf2f(h0.z));
        h0.w = f2bf(u.w); l0.w = f2bf(u.w - bf2f(h0.w));
        h1.x = f2bf(v.x); l1.x = f2bf(v.x - bf2f(h1.x));
        h1.y = f2bf(v.y); l1.y = f2bf(v.y - bf2f(h1.y));
        h1.z = f2bf(v.z); l1.z = f2bf(v.z - bf2f(h1.z));
        h1.w = f2bf(v.w); l1.w = f2bf(v.w - bf2f(h1.w));
        ((us4*)(Ch + base))[0] = h0; ((us4*)(Ch + base))[1] = h1;
        ((us4*)(Cl + base))[0] = l0; ((us4*)(Cl + base))[1] = l1;
#pragma unroll
        for (int off = 32; off; off >>= 1) s += __shfl_xor(s, off);
        if (lane == 0) cbs[w] = s;
    } else {
        int i = (bid - cbBlocks) * 256 + tid;
        int stride = xBlocks * 256;
        for (; i < n4; i += stride) {
            float4 v = ((const float4*)X)[i];
            us4 h, l;
            h.x = f2bf(v.x); l.x = f2bf(v.x - bf2f(h.x));
            h.y = f2bf(v.y); l.y = f2bf(v.y - bf2f(h.y));
            h.z = f2bf(v.z); l.z = f2bf(v.z - bf2f(h.z));
            h.w = f2bf(v.w); l.w = f2bf(v.w - bf2f(h.w));
            ((us4*)Xh)[i] = h;
            ((us4*)Xl)[i] = l;
        }
    }
}

// ---- pass 1: transposed MFMA dists + per-lane top-3 ----
// Tile: 256 codes x 128 xrows, BK=16. 8 waves: wq = w&3 (code quarter,
// 64 codes), wh = w>>2 (row half, 64 rows). Per wave 64x64 via acc[2][2].
// grid = (N/128)*KSPLIT; bid&7 = split (XCD-affine).
__global__ __launch_bounds__(512, 4) void vq_mfma_kernel(
        const unsigned short* __restrict__ Xh, const unsigned short* __restrict__ Xl,
        const unsigned short* __restrict__ Ch, const unsigned short* __restrict__ Cl,
        const float* __restrict__ cbs,
        float* __restrict__ pd1, int* __restrict__ pi1,
        float* __restrict__ pd2, int* __restrict__ pi2,
        float* __restrict__ pd3, int N, int K) {

    __shared__ unsigned short Cs_h[2][256 * 16], Cs_l[2][256 * 16];  // 8KB each buf
    __shared__ unsigned short Xs_h[2][128 * 16], Xs_l[2][128 * 16];  // 4KB each buf

    const int tid  = threadIdx.x;
    const int lane = tid & 63;
    const int w    = tid >> 6;       // 0..7
    const int wq   = w & 3;          // code quarter
    const int wh   = w >> 2;         // x-row half
    const int bid  = blockIdx.x;
    const int split     = bid & (KSPLIT - 1);
    const int rowBase   = (bid >> 3) * 128;
    const int kPerSplit = K / KSPLIT;
    const int splitBase = split * kPerSplit;
    const int NT        = kPerSplit / 256;   // col-tiles of 256 codes
    const int nSteps    = NT * 32;           // BK=16 -> 32 kt per col-tile

    // 32B rows, 2 chunks of 16B. swizzle sw(r) = ((r>>2)&1) ^ ((r>>4)&1).
    // staging: lane l covers row (l>>1) of its 32-row span, chunk l&1;
    // pre-swizzled global chunk = (l&1) ^ swS.
    const int swS  = ((lane >> 3) & 1) ^ ((lane >> 5) & 1);   // sw(row(l))
    const int cswz = ((lane & 1) ^ swS) * 8;                  // elem offset
    const size_t gC0 = (size_t)(w * 32 + (lane >> 1)) * D_DIM + cswz;
    const size_t gX0 = (size_t)(rowBase + (w & 3) * 32 + (lane >> 1)) * D_DIM + cswz;
    const int l0c = w * 512 + lane * 8;          // shorts
    const int l0x = (w & 3) * 512 + lane * 8;

    // fragment reads: row = base + (lane&31) (+{32,64} offsets: bits<5 same),
    // k-octet c = lane>>5; physical chunk = c ^ sw(row).
    const int lh   = lane >> 5;
    const int rC   = wq * 64 + (lane & 31);
    const int rX   = wh * 64 + (lane & 31);
    const int kOff = ((lh ^ ((lane >> 2) & 1) ^ ((lane >> 4) & 1))) * 8;

    float d1v[2], d2v[2], d3v[2];
    int   i1v[2], i2v[2];
#pragma unroll
    for (int nf = 0; nf < 2; ++nf) {
        d1v[nf] = 3.4e38f; d2v[nf] = 3.4e38f; d3v[nf] = 3.4e38f;
        i1v[nf] = 0x7fffffff; i2v[nf] = 0x7fffffff;
    }

    f32x16 acc[2][2];

    auto fold = [&](int ctF) {
        const int cb0 = splitBase + ctF * 256 + wq * 64 + 4 * lh;
#pragma unroll
        for (int mf = 0; mf < 2; ++mf)
#pragma unroll
            for (int rq = 0; rq < 4; ++rq) {
                float4 c2q = *(const float4*)&cbs[cb0 + mf * 32 + rq * 8];
#pragma unroll
                for (int j = 0; j < 4; ++j) {
                    const int code = cb0 + mf * 32 + rq * 8 + j;
                    const int reg  = rq * 4 + j;
                    const float c2 = (&c2q.x)[j];
#pragma unroll
                    for (int nf = 0; nf < 2; ++nf) {
                        float dist = fmaf(-2.f, acc[mf][nf][reg], c2);
                        ins3(dist, code, d1v[nf], i1v[nf], d2v[nf], i2v[nf], d3v[nf]);
                    }
                }
            }
    };

    // 3 gloads per wave per step: Cs_h, Cs_l (all waves), Xh (w<4) / Xl (w>=4)
#define STAGE(buf, s_)                                                        \
    do { int ct_ = (s_) >> 5, kt_ = (s_) & 31;                                \
        size_t cb_ = (size_t)(splitBase + ct_ * 256) * D_DIM + gC0 + kt_ * 16;\
        gload_lds16(Ch + cb_, &Cs_h[buf][l0c]);                               \
        gload_lds16(Cl + cb_, &Cs_l[buf][l0c]);                               \
        size_t xb_ = gX0 + kt_ * 16;                                          \
        if (w < 4) gload_lds16(Xh + xb_, &Xs_h[buf][l0x]);                    \
        else       gload_lds16(Xl + xb_, &Xs_l[buf][l0x]);                    \
    } while (0)

    STAGE(0, 0);

    for (int s = 0; s < nSteps; ++s) {
        const int cur = s & 1;
        const int kt  = s & 31;
        const int ct  = s >> 5;

        if (s + 1 < nSteps) {
            STAGE(cur ^ 1, s + 1);
            // 3 loads/step: outstanding = 3 (cur) + 3 (next); vmcnt(3)
            // retires exactly the current step's loads.
            asm volatile("s_waitcnt vmcnt(3)" ::: "memory");
        } else {
            asm volatile("s_waitcnt vmcnt(0)" ::: "memory");
        }
        __builtin_amdgcn_s_barrier();          // cur buffers visible

        short8 xv[2][2];   // [nf][hl]
#pragma unroll
        for (int nf = 0; nf < 2; ++nf) {
            xv[nf][0] = *(const short8*)&Xs_h[cur][(rX + nf * 32) * 16 + kOff];
            xv[nf][1] = *(const short8*)&Xs_l[cur][(rX + nf * 32) * 16 + kOff];
        }

        if (kt == 0) {                          // fold prev code-tile, reset acc
            if (s) fold(ct - 1);
#pragma unroll
            for (int mf = 0; mf < 2; ++mf)
#pragma unroll
                for (int nf = 0; nf < 2; ++nf)
#pragma unroll
                    for (int r = 0; r < 16; ++r) acc[mf][nf][r] = 0.f;
        }

#pragma unroll
        for (int mf = 0; mf < 2; ++mf) {
            short8 ch = *(const short8*)&Cs_h[cur][(rC + mf * 32) * 16 + kOff];
            short8 cl = *(const short8*)&Cs_l[cur][(rC + mf * 32) * 16 + kOff];
#pragma unroll
            for (int nf = 0; nf < 2; ++nf) {
                acc[mf][nf] = __builtin_amdgcn_mfma_f32_32x32x16_bf16(
                    ch, xv[nf][0], acc[mf][nf], 0, 0, 0);
                acc[mf][nf] = __builtin_amdgcn_mfma_f32_32x32x16_bf16(
                    cl, xv[nf][0], acc[mf][nf], 0, 0, 0);
                acc[mf][nf] = __builtin_amdgcn_mfma_f32_32x32x16_bf16(
                    ch, xv[nf][1], acc[mf][nf], 0, 0, 0);
            }
        }

        __builtin_amdgcn_sched_barrier(0);      // pin reads above end barrier
        __builtin_amdgcn_s_barrier();           // all reads of cur done
    }
#undef STAGE

    fold(NT - 1);

    // merge lane halves (l <-> l^32): same x-col, codes offset by 4*lh
#pragma unroll
    for (int nf = 0; nf < 2; ++nf) {
        float od1 = __shfl_xor(d1v[nf], 32);
        int   oi1 = __shfl_xor(i1v[nf], 32);
        float od2 = __shfl_xor(d2v[nf], 32);
        int   oi2 = __shfl_xor(i2v[nf], 32);
        float od3 = __shfl_xor(d3v[nf], 32);
        ins3(od1, oi1, d1v[nf], i1v[nf], d2v[nf], i2v[nf], d3v[nf]);
        ins3(od2, oi2, d1v[nf], i1v[nf], d2v[nf], i2v[nf], d3v[nf]);
        d3v[nf] = fminf(d3v[nf], od3);
    }

    // cross-code-quarter merge via LDS overlay on Cs_h (15*128*4B = 7.7KB)
    __syncthreads();
    float* mD1 = (float*)&Cs_h[0][0];          // [3][128]
    int*   mI1 = (int*)(mD1 + 3 * 128);
    float* mD2 = (float*)(mD1 + 6 * 128);
    int*   mI2 = (int*)(mD1 + 9 * 128);
    float* mD3 = (float*)(mD1 + 12 * 128);
    if (wq != 0 && lane < 32) {
        int e = (wq - 1) * 128;
#pragma unroll
        for (int nf = 0; nf < 2; ++nf) {
            int x = wh * 64 + nf * 32 + lane;
            mD1[e + x] = d1v[nf]; mI1[e + x] = i1v[nf];
            mD2[e + x] = d2v[nf]; mI2[e + x] = i2v[nf];
            mD3[e + x] = d3v[nf];
        }
    }
    __syncthreads();
    if (wq == 0 && lane < 32) {
#pragma unroll
        for (int nf = 0; nf < 2; ++nf) {
            int x = wh * 64 + nf * 32 + lane;
            float d1 = d1v[nf], d2 = d2v[nf], d3 = d3v[nf];
            int i1 = i1v[nf], i2 = i2v[nf];
#pragma unroll
            for (int e = 0; e < 3; ++e) {
                ins3(mD1[e * 128 + x], mI1[e * 128 + x], d1, i1, d2, i2, d3);
                ins3(mD2[e * 128 + x], mI2[e * 128 + x], d1, i1, d2, i2, d3);
                d3 = fminf(d3, mD3[e * 128 + x]);
            }
            size_t p = (size_t)split * N + (rowBase + x);
            pd1[p] = d1; pi1[p] = i1; pd2[p] = d2; pi2[p] = i2; pd3[p] = d3;
        }
    }
}

// ---- pass 2: merge splits + exact top-2 compare; block full scan for
// 3-way near-ties (expected ~0 rows/run). 128 rows per block.
__global__ __launch_bounds__(256) void combine_refine_kernel(
        const float* __restrict__ X, const float* __restrict__ CB,
        const float* __restrict__ cbs,
        const float* __restrict__ pd1, const int* __restrict__ pi1,
        const float* __restrict__ pd2, const int* __restrict__ pi2,
        const float* __restrict__ pd3,
        int* __restrict__ out, int N, int K, int S) {
    __shared__ float xs[D_DIM];
    __shared__ int rare[128];
    __shared__ int nrare;
    __shared__ float rDs[4];
    __shared__ int   rIs[4];
    const int tid = threadIdx.x;
    if (tid == 0) nrare = 0;
    __syncthreads();

    const int row = blockIdx.x * 128 + tid;
    if (tid < 128 && row < N) {
        float d1 = pd1[row], d2 = pd2[row], d3 = pd3[row];
        int i1 = pi1[row], i2 = pi2[row];
        for (int s = 1; s < S; ++s) {
            size_t p = (size_t)s * N + row;
            ins3(pd1[p], pi1[p], d1, i1, d2, i2, d3);
            ins3(pd2[p], pi2[p], d1, i1, d2, i2, d3);
            d3 = fminf(d3, pd3[p]);
        }
        int best = i1;
        if (d2 - d1 < EPS_GAP) {
            if (d3 - d1 < EPS_GAP) {
                int p = atomicAdd(&nrare, 1);
                rare[p] = row;
            } else {
                // exact fp32 top-2 compare
                const float4* xr = (const float4*)(X + (size_t)row * D_DIM);
                const float4* ca = (const float4*)(CB + (size_t)i1 * D_DIM);
                const float4* cb = (const float4*)(CB + (size_t)i2 * D_DIM);
                float dotA = 0.f, dotB = 0.f;
#pragma unroll 4
                for (int d = 0; d < D_DIM / 4; ++d) {
                    float4 xv = xr[d], av = ca[d], bv = cb[d];
                    dotA = fmaf(xv.x, av.x, dotA); dotA = fmaf(xv.y, av.y, dotA);
                    dotA = fmaf(xv.z, av.z, dotA); dotA = fmaf(xv.w, av.w, dotA);
                    dotB = fmaf(xv.x, bv.x, dotB); dotB = fmaf(xv.y, bv.y, dotB);
                    dotB = fmaf(xv.z, bv.z, dotB); dotB = fmaf(xv.w, bv.w, dotB);
                }
                float dA = fmaf(-2.f, dotA, cbs[i1]);
                float dB = fmaf(-2.f, dotB, cbs[i2]);
                best = (dB < dA || (dB == dA && i2 < i1)) ? i2 : i1;
            }
        }
        out[row] = best;
    }
    __syncthreads();
    const int nr = nrare;
    for (int r = 0; r < nr; ++r) {
        const int rrow = rare[r];
        __syncthreads();
        for (int i = tid; i < D_DIM; i += 256)
            xs[i] = X[(size_t)rrow * D_DIM + i];
        __syncthreads();
        float bd = 3.4e38f; int bi = 0x7fffffff;
        for (int c = tid; c < K; c += 256) {
            const float4* cp = (const float4*)(CB + (size_t)c * D_DIM);
            float dot = 0.f;
#pragma unroll 4
            for (int d = 0; d < D_DIM / 4; ++d) {
                float4 cv = cp[d];
                float4 xv = *(const float4*)&xs[d * 4];
                dot = fmaf(xv.x, cv.x, dot); dot = fmaf(xv.y, cv.y, dot);
                dot = fmaf(xv.z, cv.z, dot); dot = fmaf(xv.w, cv.w, dot);
            }
            float dist = fmaf(-2.f, dot, cbs[c]);
            if (dist < bd) { bd = dist; bi = c; }
        }
#pragma unroll
        for (int off = 1; off < 64; off <<= 1) {
            float od = __shfl_xor(bd, off);
            int   oi = __shfl_xor(bi, off);
            if (od < bd || (od == bd && oi < bi)) { bd = od; bi = oi; }
        }
        if ((tid & 63) == 0) { rDs[tid >> 6] = bd; rIs[tid >> 6] = bi; }
        __syncthreads();
        if (tid == 0) {
            for (int ww = 1; ww < 4; ++ww)
                if (rDs[ww] < bd || (rDs[ww] == bd && rIs[ww] < bi)) {
                    bd = rDs[ww]; bi = rIs[ww];
                }
            out[rrow] = bi;
        }
    }
}

// ================= fp32 fallback (generic shapes) =================
#define BM 128
#define BN 128
#define BD 16

__global__ __launch_bounds__(256) void cbsqr_kernel(const float* __restrict__ cb,
                                                    float* __restrict__ out, int K) {
    int gtid = blockIdx.x * blockDim.x + threadIdx.x;
    int w = gtid >> 6;
    int lane = gtid & 63;
    if (w >= K) return;
    const float4* r4 = (const float4*)(cb + (size_t)w * D_DIM) + lane * 2;
    float4 u = r4[0], v = r4[1];
    float s = u.x*u.x + u.y*u.y + u.z*u.z + u.w*u.w
            + v.x*v.x + v.y*v.y + v.z*v.z + v.w*v.w;
#pragma unroll
    for (int off = 32; off; off >>= 1) s += __shfl_xor(s, off);
    if (lane == 0) out[w] = s;
}

__global__ __launch_bounds__(128) void vq_fp32_kernel(
        const float* __restrict__ X, const float* __restrict__ CB,
        const float* __restrict__ cbs,
        float* __restrict__ pd, int* __restrict__ pi,
        int* __restrict__ out, int N, int K, int nsplit) {

    __shared__ float As[BD][BM + 4];
    __shared__ float Bs[BD][BN + 4];

    const int tid = threadIdx.x;
    const int tx = tid & 7;
    const int ty = tid >> 3;
    const int rowBase = blockIdx.x * BM;
    const int split = blockIdx.y;
    const int kPer = K / nsplit;
    const int c0 = split * kPer, c1 = c0 + kPer;
    const int ldRow = tid >> 2;
    const int ldCol = (tid & 3) * 4;

    float bestD[8]; int bestI[8];
#pragma unroll
    for (int i = 0; i < 8; ++i) { bestD[i] = 3.4e38f; bestI[i] = 0; }

    for (int ct = c0; ct < c1; ct += BN) {
        float acc[8][16];
#pragma unroll
        for (int i = 0; i < 8; ++i)
#pragma unroll
            for (int j = 0; j < 16; ++j) acc[i][j] = 0.f;

        for (int dt = 0; dt < D_DIM; dt += BD) {
#pragma unroll
            for (int p = 0; p < 4; ++p) {
                int r = ldRow + p * 32;
                float4 av = *(const float4*)&X[(size_t)(rowBase + r) * D_DIM + dt + ldCol];
                float4 bv = *(const float4*)&CB[(size_t)(ct + r) * D_DIM + dt + ldCol];
                As[ldCol + 0][r] = av.x; As[ldCol + 1][r] = av.y;
                As[ldCol + 2][r] = av.z; As[ldCol + 3][r] = av.w;
                Bs[ldCol + 0][r] = bv.x; Bs[ldCol + 1][r] = bv.y;
                Bs[ldCol + 2][r] = bv.z; Bs[ldCol + 3][r] = bv.w;
            }
            __syncthreads();
#pragma unroll
            for (int d = 0; d < BD; ++d) {
                float4 a0 = *(const float4*)&As[d][ty * 4];
                float4 a1 = *(const float4*)&As[d][64 + ty * 4];
                float4 b0 = *(const float4*)&Bs[d][ 0 + tx * 4];
                float4 b1 = *(const float4*)&Bs[d][32 + tx * 4];
                float4 b2 = *(const float4*)&Bs[d][64 + tx * 4];
                float4 b3 = *(const float4*)&Bs[d][96 + tx * 4];
                float a[8] = {a0.x,a0.y,a0.z,a0.w,a1.x,a1.y,a1.z,a1.w};
                float b[16] = {b0.x,b0.y,b0.z,b0.w, b1.x,b1.y,b1.z,b1.w,
                               b2.x,b2.y,b2.z,b2.w, b3.x,b3.y,b3.z,b3.w};
#pragma unroll
                for (int i = 0; i < 8; ++i)
#pragma unroll
                    for (int j = 0; j < 16; ++j)
                        acc[i][j] = fmaf(a[i], b[j], acc[i][j]);
            }
            __syncthreads();
        }
#pragma unroll
        for (int j = 0; j < 16; ++j) {
            int code = ct + (j >> 2) * 32 + tx * 4 + (j & 3);
            float c2v = cbs[code];
#pragma unroll
            for (int i = 0; i < 8; ++i) {
                float dist = fmaf(-2.f, acc[i][j], c2v);
                if (dist < bestD[i]) { bestD[i] = dist; bestI[i] = code; }
            }
        }
    }
#pragma unroll
    for (int i = 0; i < 8; ++i) {
        float bd = bestD[i]; int bi = bestI[i];
#pragma unroll
        for (int off = 1; off < 8; off <<= 1) {
            float od = __shfl_xor(bd, off);
            int   oi = __shfl_xor(bi, off);
            if (od < bd || (od == bd && oi < bi)) { bd = od; bi = oi; }
        }
        if (tx == 0) {
            int row = rowBase + ((i < 4) ? ty * 4 + i : 64 + ty * 4 + (i - 4));
            if (nsplit == 1) out[row] = bi;
            else {
                pd[(size_t)row * nsplit + split] = bd;
                pi[(size_t)row * nsplit + split] = bi;
            }
        }
    }
}

__global__ __launch_bounds__(256) void combine_fp32_kernel(
        const float* __restrict__ pd, const int* __restrict__ pi,
        int* __restrict__ out, int N, int S) {
    int r = blockIdx.x * blockDim.x + threadIdx.x;
    if (r >= N) return;
    float bd = pd[(size_t)r * S];
    int bi = pi[(size_t)r * S];
    for (int s = 1; s < S; ++s) {
        float d = pd[(size_t)r * S + s];
        int i = pi[(size_t)r * S + s];
        if (d < bd || (d == bd && i < bi)) { bd = d; bi = i; }
    }
    out[r] = bi;
}

// =========================== launcher ===========================
extern "C" void kernel_launch(void* const* d_in, const int* in_sizes, int n_in,
                              void* d_out, int out_size, void* d_ws, size_t ws_size,
                              hipStream_t stream) {
    const float* X  = (const float*)d_in[0];
    const float* CB = (const float*)d_in[1];
    const int N = in_sizes[0] / D_DIM;
    const int K = in_sizes[1] / D_DIM;
    int* out = (int*)d_out;

    size_t o = 0;
    auto take = [&](size_t bytes) { size_t r = o; o += (bytes + 255) & ~(size_t)255; return r; };
    size_t oCbs = take((size_t)K * 4);
    size_t oXh  = take((size_t)N * D_DIM * 2);
    size_t oXl  = take((size_t)N * D_DIM * 2);
    size_t oCh  = take((size_t)K * D_DIM * 2);
    size_t oCl  = take((size_t)K * D_DIM * 2);
    size_t oPd1 = take((size_t)N * KSPLIT * 4);
    size_t oPi1 = take((size_t)N * KSPLIT * 4);
    size_t oPd2 = take((size_t)N * KSPLIT * 4);
    size_t oPi2 = take((size_t)N * KSPLIT * 4);
    size_t oPd3 = take((size_t)N * KSPLIT * 4);
    const size_t need = o;

    char* ws = (char*)d_ws;
    float* cbs = (float*)(ws + oCbs);

    if (ws_size >= need && (N % 128) == 0 && (K % (KSPLIT * 256)) == 0) {
        unsigned short* Xh = (unsigned short*)(ws + oXh);
        unsigned short* Xl = (unsigned short*)(ws + oXl);
        unsigned short* Ch = (unsigned short*)(ws + oCh);
        unsigned short* Cl = (unsigned short*)(ws + oCl);
        float* pd1 = (float*)(ws + oPd1);
        int*   pi1 = (int*)(ws + oPi1);
        float* pd2 = (float*)(ws + oPd2);
        int*   pi2 = (int*)(ws + oPi2);
        float* pd3 = (float*)(ws + oPd3);

        const int cbBlocks = K / 4;
        const int xBlocks  = 2048;
        prep_kernel<<<cbBlocks + xBlocks, 256, 0, stream>>>(
            X, CB, Xh, Xl, Ch, Cl, cbs, N * D_DIM / 4, K, cbBlocks, xBlocks);

        vq_mfma_kernel<<<(N / 128) * KSPLIT, 512, 0, stream>>>(
            Xh, Xl, Ch, Cl, cbs, pd1, pi1, pd2, pi2, pd3, N, K);

        combine_refine_kernel<<<N / 128, 256, 0, stream>>>(
            X, CB, cbs, pd1, pi1, pd2, pi2, pd3, out, N, K, KSPLIT);
    } else {
        size_t base = ((size_t)K * 4 + 255) & ~(size_t)255;
        int nsplit = 4;
        while (nsplit > 1 &&
               (ws_size < base + (size_t)N * nsplit * 8 || (K % (nsplit * BN)) != 0))
            nsplit >>= 1;
        float* pd = (float*)(ws + base);
        int*   pi = (int*)(ws + base + (size_t)N * nsplit * 4);
        cbsqr_kernel<<<(K + 3) / 4, 256, 0, stream>>>(CB, cbs, K);
        dim3 grid(N / BM, nsplit);
        vq_fp32_kernel<<<grid, 128, 0, stream>>>(X, CB, cbs, pd, pi, out, N, K, nsplit);
        if (nsplit > 1)
            combine_fp32_kernel<<<(N + 255) / 256, 256, 0, stream>>>(pd, pi, out, N, nsplit);
    }
}